// Round 3
// baseline (262.927 us; speedup 1.0000x reference)
//
#include <hip/hip_runtime.h>

#define Bn 512
#define Cn 202
#define Pn 27
#define Nn 729
#define CHn 200
#define Kn 58
#define OUTCn 64
#define CENTERn 364   // 13*27+13
#define NCHUNK 7
#define NT 23         // col-tiles per half-image block
#define ROWS 16       // staged rows (incl. 1 pad/halo row each side of the half)
#define PCOLS 29      // 27 + 2 col pads

typedef float f32x4 __attribute__((ext_vector_type(4)));
typedef short s16x8 __attribute__((ext_vector_type(8)));
typedef short s16x4 __attribute__((ext_vector_type(4)));

static __device__ __forceinline__ unsigned short f2bf(float f) {
  unsigned u = __float_as_uint(f);
  u += 0x7fffu + ((u >> 16) & 1u);   // RNE
  return (unsigned short)(u >> 16);
}

// ---------------- Kernel A: build src permutation per batch ----------------
__global__ __launch_bounds__(256) void src_kernel(const float* __restrict__ x,
                                                  const int* __restrict__ rand_idx,
                                                  int* __restrict__ src_out) {
  int b = blockIdx.x;
  __shared__ float sp[Nn];
  __shared__ short M[Nn];
  __shared__ short z[Nn];
  __shared__ int s_num;
  int tid = threadIdx.x;
  const float* xsp = x + ((size_t)b * Cn + CHn) * Nn;
  for (int n = tid; n < Nn; n += 256) sp[n] = xsp[n];
  __syncthreads();
  float central = sp[CENTERn];
  __syncthreads();
  for (int k = tid; k < Kn; k += 256) sp[rand_idx[b * Kn + k]] = central;
  __syncthreads();
  if (tid == 0) {
    int cm = 0, cz = 0;
    for (int n = 0; n < Nn; ++n) {
      if (sp[n] == central) { M[cm] = (short)n; cm++; z[n] = -1; }
      else { z[n] = (short)cz; cz++; }
    }
    s_num = cm;
  }
  __syncthreads();
  int num_one = s_num;
  for (int n = tid; n < Nn; n += 256) {
    int zz = z[n];
    src_out[b * Nn + n] = (zz < 0) ? n : (int)M[zz % num_one];
  }
}

// ---------------- Kernel B: weights -> bf16, chunked layout Wt2[ck][r][o][32] ----------------
__global__ __launch_bounds__(256) void wprep_kernel(const float* __restrict__ W,
                                                    short* __restrict__ Wt2) {
  int idx = blockIdx.x * 256 + threadIdx.x;
  if (idx >= NCHUNK * 9 * OUTCn * 32) return;
  int ck = idx / (9 * OUTCn * 32);
  int rem = idx - ck * (9 * OUTCn * 32);
  int r = rem / (OUTCn * 32);
  int rem2 = rem - r * (OUTCn * 32);
  int o = rem2 >> 5;
  int cl = rem2 & 31;
  int c = ck * 32 + cl;
  float v = (c < CHn) ? W[((size_t)o * CHn + c) * 9 + r] : 0.f;
  Wt2[idx] = (short)f2bf(v);
}

// ---------------- Kernel C: fused gather + implicit-GEMM conv (MFMA) ----------------
// grid (2, 512): block = (half h, batch b). 512 threads = 8 waves = 2 og x 4 cg.
// Each wave: 2 o-tiles (og*32..+31) x 6 col-tiles -> acc[2][6] f32x4 (48 AGPR).
__global__ __launch_bounds__(512, 4) void conv_kernel(const float* __restrict__ x,
                                                      const short* __restrict__ Wt2,
                                                      const float* __restrict__ bias,
                                                      const int* __restrict__ src,
                                                      float* __restrict__ y) {
  __shared__ __align__(16) unsigned short Img[ROWS * PCOLS * 32];  // 29,696 B
  __shared__ __align__(16) unsigned short Aw[9 * OUTCn * 32];      // 36,864 B
  __shared__ int srcl[15 * Pn];                                    // 1,620 B

  const int h = blockIdx.x;
  const int b = blockIdx.y;
  const int tid = threadIdx.x;
  const int lane = tid & 63;
  const int wv = tid >> 6;
  const int l16 = lane & 15;
  const int kg = lane >> 4;
  const int og = wv >> 2;   // 0..1 -> o in [og*32, og*32+32)
  const int cg = wv & 3;    // col-tile group

  const int row0 = h ? 12 : -1;        // global row of local row 0
  const int n0 = h ? (12 * Pn) : 0;    // first staged real pixel
  const int lsoff = h ? 0 : 1;         // local row of first real row

  for (int i2 = tid; i2 < 15 * Pn; i2 += 512) srcl[i2] = src[b * Nn + n0 + i2];
  for (int i2 = tid; i2 < ROWS * PCOLS * 32 / 2; i2 += 512) ((unsigned int*)Img)[i2] = 0u;

  // per-lane tile geometry (chunk-invariant)
  int ibase[6];
  int ncs[6];
  bool st[6];
#pragma unroll
  for (int t = 0; t < 6; ++t) {
    int Tloc = cg * 6 + t;
    int Tc = (Tloc < NT) ? Tloc : (NT - 1);
    int T = h * NT + Tc;
    int nc = T * 16 + l16;
    if (nc > Nn - 1) nc = Nn - 1;
    int i = nc / Pn;
    int j = nc - i * Pn;
    int lr = i - row0;                       // 1..14 for both halves
    ibase[t] = ((lr - 1) * PCOLS + j) * 64 + kg * 16;
    int ncraw = (h * NT + Tloc) * 16 + l16;
    ncs[t] = ncraw;
    st[t] = (Tloc < NT) && (ncraw < Nn);
  }

  f32x4 acc[2][6];
#pragma unroll
  for (int a = 0; a < 2; ++a)
#pragma unroll
    for (int t = 0; t < 6; ++t) acc[a][t] = (f32x4){0.f, 0.f, 0.f, 0.f};

  const float* xb = x + (size_t)b * Cn * Nn;

  for (int ck = 0; ck < NCHUNK; ++ck) {
    const int c0 = ck * 32;
    __syncthreads();   // previous compute (or init) done before overwriting LDS

    // ---- stage weights: linear copy of 36,864 B (2304 x 16B), perfectly coalesced
    {
      const s16x8* wsrc = (const s16x8*)(Wt2 + (size_t)ck * (9 * OUTCn * 32));
      s16x8* wdst = (s16x8*)Aw;
      for (int i2 = tid; i2 < 9 * OUTCn * 32 / 8; i2 += 512) wdst[i2] = wsrc[i2];
    }

    // ---- stage gathered image: 405 real pixels x 8 groups of 4 channels
    for (int idx = tid; idx < 15 * Pn * 8; idx += 512) {
      int cgrp = idx & 7;          // channel group (fast) -> conflict-free ds_write pattern
      int p = idx >> 3;            // staged pixel 0..404
      int pr = p / Pn;
      int gj = p - pr * Pn;
      int ls = pr + lsoff;
      int s = srcl[p];
      int c = c0 + cgrp * 4;
      float v0, v1, v2, v3;
      if (c + 3 < CHn) {
        const float* xs = xb + (size_t)c * Nn + s;
        v0 = xs[0]; v1 = xs[Nn]; v2 = xs[2 * Nn]; v3 = xs[3 * Nn];
      } else {
        v0 = v1 = v2 = v3 = 0.f;
      }
      s16x4 w4 = {(short)f2bf(v0), (short)f2bf(v1), (short)f2bf(v2), (short)f2bf(v3)};
      *(s16x4*)((char*)Img + (ls * PCOLS + gj + 1) * 64 + cgrp * 8) = w4;
    }
    __syncthreads();

    // ---- compute: 9 shifts x 6 col-tiles x 2 o-tiles
#pragma unroll
    for (int r = 0; r < 9; ++r) {
      const int dr = r / 3, dc = r % 3;
      const char* awp = (const char*)Aw + r * (OUTCn * 64) + (og * 32 + l16) * 64 + kg * 16;
      s16x8 a0 = *(const s16x8*)(awp);
      s16x8 a1 = *(const s16x8*)(awp + 16 * 64);
      const int ioff = (dr * PCOLS + dc) * 64;
#pragma unroll
      for (int t = 0; t < 6; ++t) {
        s16x8 bf = *(const s16x8*)((const char*)Img + ibase[t] + ioff);
        acc[0][t] = __builtin_amdgcn_mfma_f32_16x16x32_bf16(a0, bf, acc[0][t], 0, 0, 0);
        acc[1][t] = __builtin_amdgcn_mfma_f32_16x16x32_bf16(a1, bf, acc[1][t], 0, 0, 0);
      }
    }
  }

  // ---- epilogue: D row = kg*4 + q (within o-tile), col = l16 -> nc
#pragma unroll
  for (int t = 0; t < 6; ++t) {
    if (st[t]) {
      int nc = ncs[t];
#pragma unroll
      for (int ot = 0; ot < 2; ++ot) {
#pragma unroll
        for (int q = 0; q < 4; ++q) {
          int o = og * 32 + ot * 16 + kg * 4 + q;
          y[((size_t)b * OUTCn + o) * Nn + nc] = acc[ot][t][q] + bias[o];
        }
      }
    }
  }
}

extern "C" void kernel_launch(void* const* d_in, const int* in_sizes, int n_in,
                              void* d_out, int out_size, void* d_ws, size_t ws_size,
                              hipStream_t stream) {
  const float* x = (const float*)d_in[0];
  const float* W = (const float*)d_in[1];
  const float* bias = (const float*)d_in[2];
  const int* rand_idx = (const int*)d_in[3];
  float* y = (float*)d_out;

  int* src = (int*)d_ws;                                   // 512*729*4 = 1,492,992 B
  short* Wt2 = (short*)((char*)d_ws + (size_t)Bn * Nn * 4); // 7*9*64*32*2 = 258,048 B

  src_kernel<<<Bn, 256, 0, stream>>>(x, rand_idx, src);
  wprep_kernel<<<(NCHUNK * 9 * OUTCn * 32 + 255) / 256, 256, 0, stream>>>(W, Wt2);
  conv_kernel<<<dim3(2, Bn), 512, 0, stream>>>(x, Wt2, bias, src, y);
}

// Round 4
// 234.266 us; speedup vs baseline: 1.1223x; 1.1223x over previous
//
#include <hip/hip_runtime.h>

#define Bn 512
#define Cn 202
#define Pn 27
#define Nn 729
#define CHn 200
#define Kn 58
#define OUTCn 64
#define CENTERn 364    // 13*27+13
#define NCHUNK 7
#define NTILE 46       // 16-col tiles covering 729 (736)
#define POOLROWS 161   // 160 pool slots + 1 zero row
#define ZSLOT 160
#define PSTR 232       // pool row stride in shorts (464 B = 116 dwords -> bank stride 20)
#define MCAP 192       // M-list entries stored per batch in ws
#define SPAD 864       // slotpad row stride (shorts) per batch in ws

typedef float f32x4 __attribute__((ext_vector_type(4)));
typedef short s16x8 __attribute__((ext_vector_type(8)));
typedef short s16x4 __attribute__((ext_vector_type(4)));

static __device__ __forceinline__ unsigned short f2bf(float f) {
  unsigned u = __float_as_uint(f);
  u += 0x7fffu + ((u >> 16) & 1u);   // RNE
  return (unsigned short)(u >> 16);
}

// ---------------- Kernel A: build slot table + masked-pool list per batch ----------------
__global__ __launch_bounds__(256) void src_kernel(const float* __restrict__ x,
                                                  const int* __restrict__ rand_idx,
                                                  short* __restrict__ slotpad_ws,
                                                  short* __restrict__ Mws,
                                                  int* __restrict__ num1_ws) {
  int b = blockIdx.x;
  __shared__ float sp[Nn];
  __shared__ short slotS[Nn];   // masked: rank; else: ~zrank
  __shared__ short M[Nn];
  __shared__ int s_num;
  int tid = threadIdx.x;
  const float* xsp = x + ((size_t)b * Cn + CHn) * Nn;
  for (int n = tid; n < Nn; n += 256) sp[n] = xsp[n];
  __syncthreads();
  float central = sp[CENTERn];
  __syncthreads();
  for (int k = tid; k < Kn; k += 256) sp[rand_idx[b * Kn + k]] = central;
  __syncthreads();
  if (tid == 0) {
    int cm = 0, cz = 0;
    for (int n = 0; n < Nn; ++n) {
      if (sp[n] == central) { M[cm] = (short)n; slotS[n] = (short)cm; cm++; }
      else { slotS[n] = (short)(~cz); cz++; }
    }
    s_num = cm;
  }
  __syncthreads();
  int num = s_num;                       // >= 1 (central pixel always masked)
  int numc = num < 160 ? num : 160;
  if (tid == 0) num1_ws[b] = numc;
  for (int m = tid; m < MCAP; m += 256) Mws[(size_t)b * MCAP + m] = (m < num) ? M[m] : (short)0;
  // padded 29x29 slot table; border -> ZSLOT (zero features)
  for (int idx = tid; idx < 841; idx += 256) {
    int pi = idx / 29, pj = idx - pi * 29;
    short v = (short)ZSLOT;
    if (pi >= 1 && pi <= 27 && pj >= 1 && pj <= 27) {
      int n = (pi - 1) * Pn + (pj - 1);
      int s0 = slotS[n];
      int sv = (s0 >= 0) ? s0 : ((~s0) % num);
      if (sv > 159) sv = 159;            // safety clamp (num_one>160 is ~12-sigma)
      v = (short)sv;
    }
    slotpad_ws[(size_t)b * SPAD + idx] = v;
  }
}

// ---------------- Kernel B: weights -> bf16, chunked layout Wt2[ck][r][o][32] ----------------
__global__ __launch_bounds__(256) void wprep_kernel(const float* __restrict__ W,
                                                    short* __restrict__ Wt2) {
  int idx = blockIdx.x * 256 + threadIdx.x;
  if (idx >= NCHUNK * 9 * OUTCn * 32) return;
  int ck = idx / (9 * OUTCn * 32);
  int rem = idx - ck * (9 * OUTCn * 32);
  int r = rem / (OUTCn * 32);
  int rem2 = rem - r * (OUTCn * 32);
  int o = rem2 >> 5;
  int cl = rem2 & 31;
  int c = ck * 32 + cl;
  float v = (c < CHn) ? W[((size_t)o * CHn + c) * 9 + r] : 0.f;
  Wt2[idx] = (short)f2bf(v);
}

// ---------------- Kernel C: pool-based implicit-GEMM conv ----------------
// 512 blocks (1/batch), 1024 thr = 16 waves. Wave w: col-tiles 3w..3w+2, ALL 4 o-tiles.
// B-fragments read Pool[slot] directly via LDS slot table -> no per-chunk image staging.
__global__ __launch_bounds__(1024, 4) void conv_kernel(const float* __restrict__ x,
                                                       const short* __restrict__ Wt2,
                                                       const float* __restrict__ bias,
                                                       const short* __restrict__ slotpad_ws,
                                                       const short* __restrict__ Mws,
                                                       const int* __restrict__ num1_ws,
                                                       float* __restrict__ y) {
  __shared__ __align__(16) short Pool[POOLROWS * PSTR];  // 74,704 B
  __shared__ __align__(16) short AwS[9 * OUTCn * 32];    // 36,864 B
  __shared__ short SlotPad[841];                         //  1,682 B

  const int b = blockIdx.x;
  const int tid = threadIdx.x;
  const int lane = tid & 63;
  const int wv = tid >> 6;        // 0..15
  const int l16 = lane & 15;
  const int kg = lane >> 4;       // 0..3

  const float* xb = x + (size_t)b * Cn * Nn;
  const int num1 = num1_ws[b];

  if (tid < 841) SlotPad[tid] = slotpad_ws[(size_t)b * SPAD + tid];

  // ---- one-time pool gather: rows [0,num1) real, rest zero. m-minor for line locality.
  {
    const short* Mb = Mws + (size_t)b * MCAP;
    for (int i = tid; i < POOLROWS * 56; i += 1024) {
      int cq = i / POOLROWS;
      int m = i - cq * POOLROWS;
      int c = cq * 4;
      float v0 = 0.f, v1 = 0.f, v2 = 0.f, v3 = 0.f;
      if (m < num1 && c < CHn) {
        int s = Mb[m];
        const float* xs = xb + (size_t)c * Nn + s;
        v0 = xs[0]; v1 = xs[Nn]; v2 = xs[2 * Nn]; v3 = xs[3 * Nn];
      }
      s16x4 w4 = {(short)f2bf(v0), (short)f2bf(v1), (short)f2bf(v2), (short)f2bf(v3)};
      *(s16x4*)((char*)Pool + m * 464 + cq * 8) = w4;
    }
  }

  // ---- per-lane geometry (chunk-invariant)
  int sbase[3];
  int ncs[3];
  bool st[3];
#pragma unroll
  for (int t = 0; t < 3; ++t) {
    int tile = wv * 3 + t;
    int nc = tile * 16 + l16;
    bool ok = (tile < NTILE) && (nc < Nn);
    int ncc = (nc < Nn) ? nc : (Nn - 1);
    int i = ncc / Pn, j = ncc - i * Pn;
    sbase[t] = (i * 29 + j) * 2;      // +((dr*29+dc)*2) gives slot of shifted pixel
    ncs[t] = ncc;
    st[t] = ok;
  }
  const int abase = l16 * 64 + kg * 16;
  const int bconst0 = kg * 16;

  f32x4 acc[4][3];
#pragma unroll
  for (int a = 0; a < 4; ++a)
#pragma unroll
    for (int t = 0; t < 3; ++t) acc[a][t] = (f32x4){0.f, 0.f, 0.f, 0.f};

  __syncthreads();

  for (int ck = 0; ck < NCHUNK; ++ck) {
    // stage weight chunk (linear, coalesced, conflict-free)
    {
      const s16x8* wsrc = (const s16x8*)(Wt2 + (size_t)ck * (9 * OUTCn * 32));
      s16x8* wdst = (s16x8*)AwS;
      for (int i = tid; i < 9 * OUTCn * 32 / 8; i += 1024) wdst[i] = wsrc[i];
    }
    __syncthreads();

    const int bconst = bconst0 + ck * 64;
#pragma unroll
    for (int r = 0; r < 9; ++r) {
      const char* ap = (const char*)AwS + abase + r * 4096;
      s16x8 a0 = *(const s16x8*)(ap);
      s16x8 a1 = *(const s16x8*)(ap + 1024);
      s16x8 a2 = *(const s16x8*)(ap + 2048);
      s16x8 a3 = *(const s16x8*)(ap + 3072);
      const int soff = ((r / 3) * 29 + (r % 3)) * 2;
#pragma unroll
      for (int t = 0; t < 3; ++t) {
        int slotv = *(const short*)((const char*)SlotPad + sbase[t] + soff);
        s16x8 bf = *(const s16x8*)((const char*)Pool + slotv * 464 + bconst);
        acc[0][t] = __builtin_amdgcn_mfma_f32_16x16x32_bf16(a0, bf, acc[0][t], 0, 0, 0);
        acc[1][t] = __builtin_amdgcn_mfma_f32_16x16x32_bf16(a1, bf, acc[1][t], 0, 0, 0);
        acc[2][t] = __builtin_amdgcn_mfma_f32_16x16x32_bf16(a2, bf, acc[2][t], 0, 0, 0);
        acc[3][t] = __builtin_amdgcn_mfma_f32_16x16x32_bf16(a3, bf, acc[3][t], 0, 0, 0);
      }
    }
    __syncthreads();   // compute done before next chunk's Aw overwrite
  }

  // ---- epilogue: D row = kg*4+q (within o-tile), col = l16 -> nc
#pragma unroll
  for (int t = 0; t < 3; ++t) {
    if (st[t]) {
      int nc = ncs[t];
#pragma unroll
      for (int ot = 0; ot < 4; ++ot) {
#pragma unroll
        for (int q = 0; q < 4; ++q) {
          int o = ot * 16 + kg * 4 + q;
          y[((size_t)b * OUTCn + o) * Nn + nc] = acc[ot][t][q] + bias[o];
        }
      }
    }
  }
}

extern "C" void kernel_launch(void* const* d_in, const int* in_sizes, int n_in,
                              void* d_out, int out_size, void* d_ws, size_t ws_size,
                              hipStream_t stream) {
  const float* x = (const float*)d_in[0];
  const float* W = (const float*)d_in[1];
  const float* bias = (const float*)d_in[2];
  const int* rand_idx = (const int*)d_in[3];
  float* y = (float*)d_out;

  // workspace layout
  short* slotpad = (short*)d_ws;                                  // 512*864*2 = 884,736 B
  short* Mws = (short*)((char*)d_ws + 884736);                    // 512*192*2 = 196,608 B
  int* num1 = (int*)((char*)d_ws + 884736 + 196608);              // 2,048 B
  short* Wt2 = (short*)((char*)d_ws + 884736 + 196608 + 2048);    // 258,048 B (16B-aligned)

  src_kernel<<<Bn, 256, 0, stream>>>(x, rand_idx, slotpad, Mws, num1);
  wprep_kernel<<<(NCHUNK * 9 * OUTCn * 32 + 255) / 256, 256, 0, stream>>>(W, Wt2);
  conv_kernel<<<Bn, 1024, 0, stream>>>(x, Wt2, bias, slotpad, Mws, num1, y);
}